// Round 1
// baseline (97.857 us; speedup 1.0000x reference)
//
#include <hip/hip_runtime.h>
#include <cstdint>

// Problem constants (from reference file)
constexpr int Bb = 8;     // batch
constexpr int Cc = 256;   // channels
constexpr int Tt = 1024;  // time
constexpr int Mm = 512;   // num_masked
constexpr int Kk = 100;   // negatives per position
#define EPSF 1e-8f
#define INV_TEMP 10.0f

// ---------------------------------------------------------------------------
// Kernel A: extract masked indices per batch row, ascending t order.
// Auto-detects mask element width (1 / 4 / 8 bytes) on device:
//   exactly Mm(=512) nonzero bytes in bytes[0,1024)  <=> 1-byte layout
//   (int32 layout puts <=256 mask entries there, int64 <=128 -> can't be 512)
//   else exactly Mm nonzero int32 in ints[0,1024)    <=> 4-byte layout
//   else 8-byte layout.
// grid = Bb blocks, 1024 threads (16 waves).
// ---------------------------------------------------------------------------
__global__ __launch_bounds__(1024)
void cl_mask_extract(const void* __restrict__ mask, int* __restrict__ idx) {
    const int b    = blockIdx.x;
    const int tid  = threadIdx.x;          // 0..1023
    const int lane = tid & 63;
    const int wave = tid >> 6;             // 0..15

    __shared__ int wcnt8[16];
    __shared__ int wcnt32[16];
    __shared__ int wcntp[16];
    __shared__ int layout_s;

    // detection counts (bytes [0,1024) and ints [0,1024) are in-bounds for all layouts)
    const uint8_t* p8  = (const uint8_t*)mask;
    const int32_t* p32 = (const int32_t*)mask;
    unsigned long long bal8  = __ballot(p8[tid]  != 0);
    unsigned long long bal32 = __ballot(p32[tid] != 0);
    if (lane == 0) { wcnt8[wave] = __popcll(bal8); wcnt32[wave] = __popcll(bal32); }
    __syncthreads();
    if (tid == 0) {
        int c8 = 0, c32 = 0;
        for (int w = 0; w < 16; ++w) { c8 += wcnt8[w]; c32 += wcnt32[w]; }
        layout_s = (c8 == Mm) ? 1 : ((c32 == Mm) ? 4 : 8);
    }
    __syncthreads();
    const int esz = layout_s;

    // read my mask bit
    const long long off = (long long)b * Tt + tid;
    int bit;
    if (esz == 1)      bit = (p8[off]  != 0);
    else if (esz == 4) bit = (p32[off] != 0);
    else               bit = (((const int64_t*)mask)[off] != 0);

    // block-wide exclusive prefix via ballot/popcount
    unsigned long long bp = __ballot(bit);
    if (lane == 0) wcntp[wave] = __popcll(bp);
    __syncthreads();
    int base = 0;
    for (int w = 0; w < wave; ++w) base += wcntp[w];
    const int rank = base + __popcll(bp & ((1ull << lane) - 1ull));
    if (bit && rank < Mm) idx[b * Mm + rank] = tid;
}

// ---------------------------------------------------------------------------
// Kernel B: per-(b,m) cosine logits + logsumexp.
// grid = Bb*Mm (=4096) blocks, 256 threads (4 waves).
// Wave w, sub-group s = (lane>>4) handles k = it*16 + w*4 + s.
// Within a 16-lane group, lane q = lane&15 owns c in {j*64 + q*4 .. +3}
// -> each float4 global load is 256B contiguous per group (coalesced),
//    LDS ctx float4 reads are conflict-free (bank stride 4, 2-way max).
// ---------------------------------------------------------------------------
__global__ __launch_bounds__(256)
void cl_main(const float* __restrict__ context,
             const float* __restrict__ positive,
             const float* __restrict__ negatives,
             const int*   __restrict__ idx,
             float*       __restrict__ lossbuf) {
    const int bm   = blockIdx.x;           // 0..4095
    const int b    = bm >> 9;              // /512
    const int tid  = threadIdx.x;          // 0..255
    const int lane = tid & 63;
    const int wave = tid >> 6;             // 0..3
    const int q    = lane & 15;
    const int ks   = lane >> 4;            // 0..3

    __shared__ __align__(16) float ctx_s[Cc];
    __shared__ float red[4][3];
    __shared__ float logits[Kk + 1];
    __shared__ float inv_na_s;

    const int t = idx[bm];

    // gather ctx/pos column (stride Tt)
    const float cv = context [((long long)b * Cc + tid) * Tt + t];
    const float pv = positive[((long long)b * Cc + tid) * Tt + t];
    ctx_s[tid] = cv;

    // block reduce: ||ctx||^2, ||pos||^2, dot(ctx,pos)
    float s0 = cv * cv, s1 = pv * pv, s2 = cv * pv;
    #pragma unroll
    for (int d = 32; d >= 1; d >>= 1) {
        s0 += __shfl_xor(s0, d);
        s1 += __shfl_xor(s1, d);
        s2 += __shfl_xor(s2, d);
    }
    if (lane == 0) { red[wave][0] = s0; red[wave][1] = s1; red[wave][2] = s2; }
    __syncthreads();
    if (tid == 0) {
        const float na2 = red[0][0] + red[1][0] + red[2][0] + red[3][0];
        const float np2 = red[0][1] + red[1][1] + red[2][1] + red[3][1];
        const float dcp = red[0][2] + red[1][2] + red[2][2] + red[3][2];
        const float na = fmaxf(sqrtf(na2), EPSF);
        const float np = fmaxf(sqrtf(np2), EPSF);
        logits[0] = dcp / (na * np) * INV_TEMP;
        inv_na_s  = 1.0f / na;
    }
    __syncthreads();
    const float inv_na = inv_na_s;

    // each lane's 16 normalized ctx values -> registers (c = j*64 + q*4 + i)
    const float4* c4 = (const float4*)ctx_s;
    float4 cr[4];
    #pragma unroll
    for (int j = 0; j < 4; ++j) {
        float4 v = c4[j * 16 + q];
        v.x *= inv_na; v.y *= inv_na; v.z *= inv_na; v.w *= inv_na;
        cr[j] = v;
    }

    // negatives stream: 16 k per iteration (4 waves x 4 sub-k)
    const long long nbase = (long long)bm * Kk * Cc;
    #pragma unroll 1
    for (int it = 0; it < 7; ++it) {
        const int k = it * 16 + wave * 4 + ks;
        float dotp = 0.f, sq = 0.f;
        if (k < Kk) {
            const float4* np4 = (const float4*)(negatives + nbase + (long long)k * Cc);
            #pragma unroll
            for (int j = 0; j < 4; ++j) {
                const float4 nv = np4[j * 16 + q];
                dotp += cr[j].x * nv.x + cr[j].y * nv.y + cr[j].z * nv.z + cr[j].w * nv.w;
                sq   += nv.x * nv.x + nv.y * nv.y + nv.z * nv.z + nv.w * nv.w;
            }
        }
        // reduce within 16-lane group
        #pragma unroll
        for (int d = 1; d <= 8; d <<= 1) {
            dotp += __shfl_xor(dotp, d);
            sq   += __shfl_xor(sq, d);
        }
        if (k < Kk && q == 0) {
            const float nb = fmaxf(sqrtf(sq), EPSF);
            logits[1 + k] = dotp / nb * INV_TEMP;
        }
    }
    __syncthreads();

    // logsumexp over 101 logits (wave 0)
    if (wave == 0) {
        const float a  = logits[lane];
        const float bb = (lane + 64 <= Kk) ? logits[lane + 64] : -1e30f;
        float mx = fmaxf(a, bb);
        #pragma unroll
        for (int d = 32; d >= 1; d >>= 1) mx = fmaxf(mx, __shfl_xor(mx, d));
        float e = expf(a - mx) + expf(bb - mx);
        #pragma unroll
        for (int d = 32; d >= 1; d >>= 1) e += __shfl_xor(e, d);
        if (lane == 0) lossbuf[bm] = mx + logf(e) - logits[0];
    }
}

// ---------------------------------------------------------------------------
// Kernel C: deterministic mean over 4096 per-(b,m) losses.
// ---------------------------------------------------------------------------
__global__ __launch_bounds__(256)
void cl_reduce(const float* __restrict__ lossbuf, float* __restrict__ out) {
    const int tid = threadIdx.x;   // 0..255
    float s = 0.f;
    #pragma unroll
    for (int i = 0; i < 16; ++i) s += lossbuf[tid * 16 + i];
    #pragma unroll
    for (int d = 32; d >= 1; d >>= 1) s += __shfl_xor(s, d);
    __shared__ float ws[4];
    if ((tid & 63) == 0) ws[tid >> 6] = s;
    __syncthreads();
    if (tid == 0) out[0] = (ws[0] + ws[1] + ws[2] + ws[3]) * (1.0f / (Bb * Mm));
}

extern "C" void kernel_launch(void* const* d_in, const int* in_sizes, int n_in,
                              void* d_out, int out_size, void* d_ws, size_t ws_size,
                              hipStream_t stream) {
    const float* context   = (const float*)d_in[0];
    const float* positive  = (const float*)d_in[1];
    const float* negatives = (const float*)d_in[2];
    const void*  mask      = d_in[3];
    // d_in[4] = num_masked (512) — hardcoded as Mm.

    int*   idx     = (int*)d_ws;                                   // 4096 ints
    float* lossbuf = (float*)((char*)d_ws + Bb * Mm * sizeof(int)); // 4096 floats

    cl_mask_extract<<<Bb, 1024, 0, stream>>>(mask, idx);
    cl_main<<<Bb * Mm, 256, 0, stream>>>(context, positive, negatives, idx, lossbuf);
    cl_reduce<<<1, 256, 0, stream>>>(lossbuf, (float*)d_out);
}